// Round 1
// baseline (58595.416 us; speedup 1.0000x reference)
//
#include <hip/hip_runtime.h>
#include <hip/hip_bf16.h>
#include <cstddef>

#define B_ 128
#define T_ 256
#define H_ 512
#define H4_ 2048

__device__ __forceinline__ float rcp_f(float x) { return __builtin_amdgcn_rcpf(x); }
__device__ __forceinline__ float sigf(float x) { return rcp_f(1.0f + __expf(-x)); }
__device__ __forceinline__ float tanh_f(float x) {
  float p = __expf(x + x);                 // e^{2x}
  return fmaf(-2.0f, rcp_f(1.0f + p), 1.0f);  // 1 - 2/(1+e^{2x})
}
__device__ __forceinline__ float4 ld4(const float* p) { return *reinterpret_cast<const float4*>(p); }
__device__ __forceinline__ void st4(float* p, float4 v) { *reinterpret_cast<float4*>(p) = v; }
__device__ __forceinline__ void fma4(float4& a, float s, float4 w) {
  a.x = fmaf(s, w.x, a.x); a.y = fmaf(s, w.y, a.y);
  a.z = fmaf(s, w.z, a.z); a.w = fmaf(s, w.w, a.w);
}

// ---------------- init: e = 1, d0 = 1, d1 = 0 ----------------
__global__ __launch_bounds__(256) void init_kernel(float* e, float* d0, float* d1) {
  int idx = blockIdx.x * 256 + threadIdx.x;
  if (idx < B_ * T_) e[idx] = 1.0f;
  int r = idx - B_ * T_;
  if (r >= 0 && r < B_) d0[r] = 1.0f;
  r -= B_;
  if (r >= 0 && r < B_) d1[r] = 0.0f;
}

// ---------------- w1e = enc[32768,512] @ W1[512,512] (fp32, 64x64 tile) ----------------
__global__ __launch_bounds__(256) void w1e_kernel(const float* __restrict__ A,
                                                  const float* __restrict__ Bw,
                                                  float* __restrict__ C) {
  __shared__ float As[32][68];  // As[k][i] (transposed for b128 i-reads)
  __shared__ float Bs[32][68];  // Bs[k][j]
  const int i0 = blockIdx.x * 64;
  const int j0 = blockIdx.y * 64;
  const int tx = threadIdx.x & 15, ty = threadIdx.x >> 4;
  float4 acc0 = make_float4(0,0,0,0), acc1 = acc0, acc2 = acc0, acc3 = acc0;
  for (int k0 = 0; k0 < H_; k0 += 32) {
#pragma unroll
    for (int q = 0; q < 2; q++) {
      int idx = q * 256 + threadIdx.x;
      int ai = idx >> 3, ak = (idx & 7) << 2;           // 64 i x 8 kquads
      float4 av = ld4(A + (size_t)(i0 + ai) * H_ + k0 + ak);
      As[ak][ai] = av.x; As[ak + 1][ai] = av.y; As[ak + 2][ai] = av.z; As[ak + 3][ai] = av.w;
      int bk = idx >> 4, bj = (idx & 15) << 2;          // 32 k x 16 jquads
      st4(&Bs[bk][bj], ld4(Bw + (size_t)(k0 + bk) * H_ + j0 + bj));
    }
    __syncthreads();
#pragma unroll
    for (int kk = 0; kk < 32; kk++) {
      float4 a = ld4(&As[kk][ty << 2]);
      float4 bv = ld4(&Bs[kk][tx << 2]);
      fma4(acc0, a.x, bv); fma4(acc1, a.y, bv); fma4(acc2, a.z, bv); fma4(acc3, a.w, bv);
    }
    __syncthreads();
  }
  size_t base = (size_t)(i0 + (ty << 2)) * H_ + j0 + (tx << 2);
  st4(&C[base], acc0); st4(&C[base + H_], acc1);
  st4(&C[base + 2 * H_], acc2); st4(&C[base + 3 * H_], acc3);
}

// ---------------- gates: z = (e@Wk)/dPrev + h@Wr + b -> LSTM -> hNew,c ----------------
// Also writes probs row (step-1) = e/dPrev to out, and zeroes dCur.
// Grid 512 = 8 b-tiles(16b) x 64 col-tiles(8 h-cols x 4 gate-quadrants). Block 128 thr.
__global__ __launch_bounds__(128) void gates_kernel(
    const float* __restrict__ e, const float* __restrict__ dPrev,
    const float* __restrict__ hPrev, const float* __restrict__ Wk,
    const float* __restrict__ Wr, const float* __restrict__ bias,
    float* __restrict__ c, float* __restrict__ hNew,
    float* __restrict__ dCur, float* __restrict__ out, int step) {
  __shared__ float red[8][16][36];  // [kg][b][cc], padded stride vs bank conflicts
  const int ct = blockIdx.x & 63;
  const int bt = blockIdx.x >> 6;
  const int b0 = bt << 4;
  const int jh0 = ct << 3;
  const int tid = threadIdx.x;
  const int kg = tid >> 4;          // 0..7 k-split groups
  const int cb = tid & 15;
  const int cg = cb & 7;            // 8 col-groups of 4 cols
  const int bg = cb >> 3;           // 2 b-groups of 8
  const int quad = cg >> 1;         // gate quadrant (i,f,g,o)
  const int sub = cg & 1;
  const int colbase = quad * H_ + jh0 + (sub << 2);
  const int bbase = b0 + (bg << 3);

  float4 accE[8], accH[8];
#pragma unroll
  for (int i = 0; i < 8; i++) { accE[i] = make_float4(0,0,0,0); accH[i] = make_float4(0,0,0,0); }

  // e-part: K=256, this kg covers [kg*32, kg*32+32)
#pragma unroll 2
  for (int kk = 0; kk < 32; kk += 4) {
    int k = (kg << 5) + kk;
    const float* wp = Wk + (size_t)k * H4_ + colbase;
    float4 w0 = ld4(wp), w1 = ld4(wp + H4_), w2 = ld4(wp + 2 * H4_), w3 = ld4(wp + 3 * H4_);
#pragma unroll
    for (int bi = 0; bi < 8; bi++) {
      float4 s = ld4(e + ((bbase + bi) << 8) + k);
      fma4(accE[bi], s.x, w0); fma4(accE[bi], s.y, w1);
      fma4(accE[bi], s.z, w2); fma4(accE[bi], s.w, w3);
    }
  }
  // h-part: K=512, this kg covers [kg*64, kg*64+64)
#pragma unroll 2
  for (int kk = 0; kk < 64; kk += 4) {
    int k = (kg << 6) + kk;
    const float* wp = Wr + (size_t)k * H4_ + colbase;
    float4 w0 = ld4(wp), w1 = ld4(wp + H4_), w2 = ld4(wp + 2 * H4_), w3 = ld4(wp + 3 * H4_);
#pragma unroll
    for (int bi = 0; bi < 8; bi++) {
      float4 s = ld4(hPrev + ((bbase + bi) << 9) + k);
      fma4(accH[bi], s.x, w0); fma4(accH[bi], s.y, w1);
      fma4(accH[bi], s.z, w2); fma4(accH[bi], s.w, w3);
    }
  }
  // combine: z_partial = accE/dPrev + accH
#pragma unroll
  for (int bi = 0; bi < 8; bi++) {
    int b = bbase + bi;
    float invd = 1.0f / dPrev[b];
    float4 z;
    z.x = fmaf(accE[bi].x, invd, accH[bi].x);
    z.y = fmaf(accE[bi].y, invd, accH[bi].y);
    z.z = fmaf(accE[bi].z, invd, accH[bi].z);
    z.w = fmaf(accE[bi].w, invd, accH[bi].w);
    st4(&red[kg][(bg << 3) + bi][cg << 2], z);
  }
  __syncthreads();
  // reduce over kg + LSTM epilogue: 128 threads = 16 b x 8 jh
  {
    const int bi = tid >> 3, jl = tid & 7;
    float z[4];
#pragma unroll
    for (int q = 0; q < 4; q++) {
      int cc = (q << 3) + jl;
      float sum = 0.0f;
#pragma unroll
      for (int g = 0; g < 8; g++) sum += red[g][bi][cc];
      z[q] = sum + bias[q * H_ + jh0 + jl];
    }
    int b = b0 + bi, jg = jh0 + jl;
    float cv = c[(b << 9) + jg];
    float cn = sigf(z[1]) * cv + sigf(z[0]) * tanh_f(z[2]);   // f*c + i*tanh(g)
    float hn = sigf(z[3]) * tanh_f(cn);                        // o*tanh(c_new)
    c[(b << 9) + jg] = cn;
    hNew[(b << 9) + jg] = hn;
  }
  // write probs of previous step (8 blocks with ct==0 cover all b)
  if (ct == 0 && step > 0) {
    float* orow = out + (size_t)(step - 1) * T_;
    for (int r = 0; r < 32; r++) {
      int idx = (r << 7) + tid;             // 0..4095 -> 16b x 256t
      int bb = b0 + (idx >> 8), t = idx & 255;
      orow[(size_t)bb * T_ * T_ + t] = e[(bb << 8) + t] / dPrev[bb];
    }
  }
  // zero the accumulator the upcoming score kernel will use
  if (blockIdx.x == 1 && tid < B_) dCur[tid] = 0.0f;
}

// ---------------- w2d = hNew[128,512] @ W2[512,512] ----------------
// Grid 256 = 8 b-tiles(16b) x 32 col-tiles(16 cols). Block 128 thr (16 kg x (4cg x 2bg)).
__global__ __launch_bounds__(128) void w2d_kernel(const float* __restrict__ h,
                                                  const float* __restrict__ W2,
                                                  float* __restrict__ w2d) {
  __shared__ float red[16][16][20];
  const int ct = blockIdx.x & 31;
  const int bt = blockIdx.x >> 5;
  const int b0 = bt << 4, j0 = ct << 4;
  const int tid = threadIdx.x;
  const int kg = tid >> 3;          // 0..15, k-range 32
  const int cb = tid & 7;
  const int cg = cb & 3;
  const int bg = cb >> 2;
  const int col0 = j0 + (cg << 2);
  const int bbase = b0 + (bg << 3);
  float4 acc[8];
#pragma unroll
  for (int i = 0; i < 8; i++) acc[i] = make_float4(0,0,0,0);
#pragma unroll 2
  for (int kk = 0; kk < 32; kk += 4) {
    int k = (kg << 5) + kk;
    const float* wp = W2 + (size_t)k * H_ + col0;
    float4 w0 = ld4(wp), w1 = ld4(wp + H_), w2 = ld4(wp + 2 * H_), w3 = ld4(wp + 3 * H_);
#pragma unroll
    for (int bi = 0; bi < 8; bi++) {
      float4 s = ld4(h + ((bbase + bi) << 9) + k);
      fma4(acc[bi], s.x, w0); fma4(acc[bi], s.y, w1);
      fma4(acc[bi], s.z, w2); fma4(acc[bi], s.w, w3);
    }
  }
#pragma unroll
  for (int bi = 0; bi < 8; bi++) st4(&red[kg][(bg << 3) + bi][cg << 2], acc[bi]);
  __syncthreads();
#pragma unroll
  for (int q = 0; q < 2; q++) {
    int oi = (q << 7) + tid;          // 256 outputs = 16b x 16c
    int bi = oi >> 4, cc = oi & 15;
    float sum = 0.0f;
#pragma unroll
    for (int g = 0; g < 16; g++) sum += red[g][bi][cc];
    w2d[((b0 + bi) << 9) + j0 + cc] = sum;
  }
}

// ---------------- score: e[b,t] = exp(V . tanh(w1e[b,t,:] + w2d[b,:])), d[b] += e ----------------
// Grid 8192 = 128 b x 64 t-groups; block 256 = 4 waves, one (b,t) row per wave.
__global__ __launch_bounds__(256) void score_kernel(const float* __restrict__ w1e,
                                                    const float* __restrict__ w2d,
                                                    const float* __restrict__ V,
                                                    float* __restrict__ ebuf,
                                                    float* __restrict__ d) {
  const int b = blockIdx.x >> 6;
  const int t = ((blockIdx.x & 63) << 2) + (threadIdx.x >> 6);
  const int lane = threadIdx.x & 63;
  const int hh = lane << 2;
  const float* row = w1e + ((size_t)((b << 8) + t) << 9);
  float4 x0 = ld4(row + hh), x1 = ld4(row + 256 + hh);
  float4 u0 = ld4(w2d + (b << 9) + hh), u1 = ld4(w2d + (b << 9) + 256 + hh);
  float4 v0 = ld4(V + hh), v1 = ld4(V + 256 + hh);
  float acc;
  acc = tanh_f(x0.x + u0.x) * v0.x;
  acc = fmaf(tanh_f(x0.y + u0.y), v0.y, acc);
  acc = fmaf(tanh_f(x0.z + u0.z), v0.z, acc);
  acc = fmaf(tanh_f(x0.w + u0.w), v0.w, acc);
  acc = fmaf(tanh_f(x1.x + u1.x), v1.x, acc);
  acc = fmaf(tanh_f(x1.y + u1.y), v1.y, acc);
  acc = fmaf(tanh_f(x1.z + u1.z), v1.z, acc);
  acc = fmaf(tanh_f(x1.w + u1.w), v1.w, acc);
#pragma unroll
  for (int m = 32; m > 0; m >>= 1) acc += __shfl_xor(acc, m, 64);
  if (lane == 0) {
    float ev = __expf(acc);
    ebuf[(b << 8) + t] = ev;
    atomicAdd(d + b, ev);
  }
}

// ---------------- final: write probs row 255 ----------------
__global__ __launch_bounds__(256) void final_kernel(const float* __restrict__ ebuf,
                                                    const float* __restrict__ dPrev,
                                                    float* __restrict__ out) {
  int idx = blockIdx.x * 256 + threadIdx.x;   // 0..32767
  int b = idx >> 8, t = idx & 255;
  out[(size_t)b * T_ * T_ + 255 * T_ + t] = ebuf[idx] / dPrev[b];
}

extern "C" void kernel_launch(void* const* d_in, const int* in_sizes, int n_in,
                              void* d_out, int out_size, void* d_ws, size_t ws_size,
                              hipStream_t stream) {
  const float* enc  = (const float*)d_in[0];
  const float* h0   = (const float*)d_in[1];
  const float* c0   = (const float*)d_in[2];
  const float* W1   = (const float*)d_in[3];
  const float* W2   = (const float*)d_in[4];
  const float* V    = (const float*)d_in[5];
  const float* Wk   = (const float*)d_in[6];
  const float* Wr   = (const float*)d_in[7];
  const float* bias = (const float*)d_in[8];
  float* out = (float*)d_out;
  float* ws = (float*)d_ws;

  float* w1e = ws;                       size_t o = (size_t)B_ * T_ * H_;
  float* hA  = ws + o; o += B_ * H_;
  float* hB  = ws + o; o += B_ * H_;
  float* cb  = ws + o; o += B_ * H_;
  float* w2d = ws + o; o += B_ * H_;
  float* eb  = ws + o; o += B_ * T_;
  float* d0  = ws + o; o += 256;
  float* d1  = ws + o; o += 256;

  hipMemcpyAsync(hA, h0, sizeof(float) * B_ * H_, hipMemcpyDeviceToDevice, stream);
  hipMemcpyAsync(cb, c0, sizeof(float) * B_ * H_, hipMemcpyDeviceToDevice, stream);
  init_kernel<<<130, 256, 0, stream>>>(eb, d0, d1);
  w1e_kernel<<<dim3(512, 8), 256, 0, stream>>>(enc, W1, w1e);

  float* dP = d0; float* dC = d1;
  float* hP = hA; float* hN = hB;
  for (int s = 0; s < T_; s++) {
    gates_kernel<<<512, 128, 0, stream>>>(eb, dP, hP, Wk, Wr, bias, cb, hN, dC, out, s);
    w2d_kernel<<<256, 128, 0, stream>>>(hN, W2, w2d);
    score_kernel<<<8192, 256, 0, stream>>>(w1e, w2d, V, eb, dC);
    float* tmp = dP; dP = dC; dC = tmp;
    tmp = hP; hP = hN; hN = tmp;
  }
  final_kernel<<<128, 256, 0, stream>>>(eb, dP, out);
}